// Round 1
// baseline (644.819 us; speedup 1.0000x reference)
//
#include <hip/hip_runtime.h>
#include <cstdint>

typedef __attribute__((ext_vector_type(8))) short short8;
typedef __attribute__((ext_vector_type(4))) float f32x4;

#define THETA 0.7f
#define SCALE 0.17677669529663687f

__device__ __forceinline__ ushort f2b(float f) {
    uint32_t u = __float_as_uint(f);
    u += 0x7FFFu + ((u >> 16) & 1u);
    return (ushort)(u >> 16);
}
__device__ __forceinline__ float b2f(ushort b) {
    return __uint_as_float(((uint32_t)b) << 16);
}

// ---------------- K1: pad + cast + NCHW->NHWC transpose ----------------
// x[8][256][64][64] f32 -> xp[8][66][66][256] bf16 (borders pre-zeroed by memset)
__global__ __launch_bounds__(256) void k_pad(const float* __restrict__ x, ushort* __restrict__ xp) {
    int b = blockIdx.x >> 6, y = blockIdx.x & 63;
    int t = threadIdx.x;
    __shared__ float buf[64][65];
    for (int cc = 0; cc < 4; ++cc) {
        __syncthreads();
#pragma unroll
        for (int i = 0; i < 16; ++i) {
            int idx = i * 256 + t;
            int c = idx >> 6, xx = idx & 63;
            buf[c][xx] = x[(((size_t)b * 256 + cc * 64 + c) << 12) + (y << 6) + xx];
        }
        __syncthreads();
#pragma unroll
        for (int i = 0; i < 16; ++i) {
            int idx = i * 256 + t;
            int xx = idx >> 6, c = idx & 63;
            xp[((size_t)(b * 66 + y + 1) * 66 + (xx + 1)) * 256 + cc * 64 + c] = f2b(buf[c][xx]);
        }
    }
}

// ---------------- K2a: fold qkv weights (conv-dif + BN scale) -> bf16 [o][p*256+c] ----
__global__ __launch_bounds__(256) void k_foldw(const float* __restrict__ w, const float* __restrict__ s,
                                               ushort* __restrict__ Wa) {
    int o = blockIdx.x, c = threadIdx.x;
    const float* wp = w + ((size_t)o * 256 + c) * 9;
    float v[9];
#pragma unroll
    for (int p = 0; p < 9; ++p) v[p] = wp[p];
    float hv = v[1] + v[3] + v[4] + v[5] + v[7];
    v[4] -= THETA * hv;
    float sc = s[o];
#pragma unroll
    for (int p = 0; p < 9; ++p)
        Wa[(size_t)o * 2304 + p * 256 + c] = f2b(v[p] * sc);
}

// ---------------- K2b: fold proj weights (transpose + scale) --------------------
__global__ __launch_bounds__(256) void k_foldp(const float* __restrict__ w, const float* __restrict__ s,
                                               float* __restrict__ pwT) {
    int c = blockIdx.x, o = threadIdx.x;
    pwT[(size_t)c * 256 + o] = w[(size_t)o * 256 + c] * s[o];
}

// ---------------- K3: qkv conv as implicit-im2col bf16 MFMA GEMM ----------------
// D[o][pix] = sum_k Wa[o][k] * im2col[k][pix],  k = p*256+c, 72 K-steps of 32
__global__ __launch_bounds__(256) void k_conv(const ushort* __restrict__ xp, const ushort* __restrict__ Wa,
                                              const float* __restrict__ qbias, float* __restrict__ qkv) {
    __shared__ ushort Al[128][40];
    __shared__ ushort Bl[128][40];
    const int t = threadIdx.x;
    const int bid = blockIdx.x;
    const int b = bid / 192;
    const int ob = (bid % 192) >> 5;
    const int pb = bid & 31;
    const int o0 = ob << 7;
    const int lane = t & 63;
    const int w = t >> 6;
    const int rw = t >> 2;  // 0..63
    const int q4 = t & 3;
    const ushort* Ag0 = Wa + (size_t)(o0 + rw) * 2304 + q4 * 8;
    const ushort* Ag1 = Ag0 + (size_t)64 * 2304;
    const int y0 = pb * 2;
    const size_t xb = (size_t)b * 66 * 66 * 256;

    f32x4 acc[4][4] = {};

    const int ow2 = (w >> 1) << 6;
    const int pw2 = (w & 1) << 6;
    const int fr = lane & 15;
    const int fs = (lane >> 4) << 3;

    uint4 ra0, ra1, rb0, rb1;
    auto loadk = [&](int kn) {
        int pp = kn >> 3;
        int c0 = (kn & 7) << 5;
        int ky = pp / 3, kx = pp - ky * 3;
        ra0 = *(const uint4*)(Ag0 + kn * 32);
        ra1 = *(const uint4*)(Ag1 + kn * 32);
        const ushort* bp = xp + xb + ((size_t)((y0 + ky) * 66 + (rw + kx))) * 256 + c0 + q4 * 8;
        rb0 = *(const uint4*)bp;
        rb1 = *(const uint4*)(bp + 66 * 256);
    };
    loadk(0);
    for (int kc = 0; kc < 72; ++kc) {
        if (kc) __syncthreads();
        *(uint4*)&Al[rw][q4 * 8] = ra0;
        *(uint4*)&Al[rw + 64][q4 * 8] = ra1;
        *(uint4*)&Bl[rw][q4 * 8] = rb0;
        *(uint4*)&Bl[rw + 64][q4 * 8] = rb1;
        __syncthreads();
        if (kc < 71) loadk(kc + 1);
        short8 af[4], bf[4];
#pragma unroll
        for (int i = 0; i < 4; ++i) af[i] = *(const short8*)&Al[ow2 + i * 16 + fr][fs];
#pragma unroll
        for (int j = 0; j < 4; ++j) bf[j] = *(const short8*)&Bl[pw2 + j * 16 + fr][fs];
#pragma unroll
        for (int i = 0; i < 4; ++i)
#pragma unroll
            for (int j = 0; j < 4; ++j)
                acc[i][j] = __builtin_amdgcn_mfma_f32_16x16x32_bf16(af[i], bf[j], acc[i][j], 0, 0, 0);
    }
    const int pbase = pb * 128 + pw2 + (lane & 15);
#pragma unroll
    for (int i = 0; i < 4; ++i) {
        int o = o0 + ow2 + i * 16 + (lane >> 4) * 4;
#pragma unroll
        for (int r = 0; r < 4; ++r) {
            float bias = qbias[o + r];
            float* dst = qkv + ((size_t)b * 768 + o + r) * 4096 + pbase;
#pragma unroll
            for (int j = 0; j < 4; ++j)
                dst[j * 16] = acc[i][j][r] + bias;
        }
    }
}

// ---------------- K4: agent pooling (8x8 block mean of q) ----------------
__global__ __launch_bounds__(256) void k_pool(const float* __restrict__ qkv, float* __restrict__ ap) {
    int flat = blockIdx.x * 256 + threadIdx.x;  // [0, 131072)
    int n = flat & 63;
    int c = (flat >> 6) & 255;
    int b = flat >> 14;
    int py = n >> 3, px = n & 7;
    const float* qp = qkv + ((size_t)b * 768 + c) * 4096 + (py * 8) * 64 + px * 8;
    float sum = 0;
#pragma unroll
    for (int yy = 0; yy < 8; ++yy)
#pragma unroll
        for (int xx = 0; xx < 8; ++xx) sum += qp[yy * 64 + xx];
    ap[((size_t)b * 256 + c) * 64 + n] = sum * (1.0f / 64.0f);
}

// ---------------- K5: stage-1 attention partials (agents attend to keys) --------
// no-max softmax: partial s[n] = sum exp(l), partial acc[n][d] = sum exp(l)*v[d]
__global__ __launch_bounds__(256) void k_att1(const float* __restrict__ qkv, const float* __restrict__ ap,
                                              float* __restrict__ attn_g, float* __restrict__ s_g) {
    const int bid = blockIdx.x;
    const int seg = bid & 3, h = (bid >> 2) & 7, b = bid >> 5;
    const int t = threadIdx.x;
    __shared__ float a_s[64][36];   // [n][d], pre-scaled
    __shared__ ushort EL[256][68];  // [pix][n] bf16
    __shared__ ushort vL[256][40];  // [pix][d] bf16
#pragma unroll
    for (int i = 0; i < 8; ++i) {
        int idx = i * 256 + t;
        int n = idx & 63, d = idx >> 6;
        a_s[n][d] = ap[((size_t)b * 256 + h * 32 + d) * 64 + n] * SCALE;
    }
    const float* kb = qkv + ((size_t)b * 768 + 256 + h * 32) * 4096;
    const float* vb = qkv + ((size_t)b * 768 + 512 + h * 32) * 4096;
    const int n_own = t >> 2;
    const int dl = t & 3;
    float accr[8] = {0, 0, 0, 0, 0, 0, 0, 0};
    float s_acc = 0.f;
    __syncthreads();
    for (int chunk = 0; chunk < 4; ++chunk) {
        int pix = (seg * 4 + chunk) * 256 + t;
        float kr[32];
#pragma unroll
        for (int d = 0; d < 32; ++d) kr[d] = kb[(size_t)d * 4096 + pix];
#pragma unroll
        for (int i = 0; i < 4; ++i) {
            uint4 pk;
            pk.x = (uint32_t)f2b(vb[(size_t)(8 * i + 0) * 4096 + pix]) |
                   ((uint32_t)f2b(vb[(size_t)(8 * i + 1) * 4096 + pix]) << 16);
            pk.y = (uint32_t)f2b(vb[(size_t)(8 * i + 2) * 4096 + pix]) |
                   ((uint32_t)f2b(vb[(size_t)(8 * i + 3) * 4096 + pix]) << 16);
            pk.z = (uint32_t)f2b(vb[(size_t)(8 * i + 4) * 4096 + pix]) |
                   ((uint32_t)f2b(vb[(size_t)(8 * i + 5) * 4096 + pix]) << 16);
            pk.w = (uint32_t)f2b(vb[(size_t)(8 * i + 6) * 4096 + pix]) |
                   ((uint32_t)f2b(vb[(size_t)(8 * i + 7) * 4096 + pix]) << 16);
            *(uint4*)&vL[t][i * 8] = pk;
        }
#pragma unroll 1
        for (int np = 0; np < 32; ++np) {
            float l0 = 0, l1 = 0;
#pragma unroll
            for (int dq = 0; dq < 8; ++dq) {
                f32x4 a0 = *(const f32x4*)&a_s[2 * np][dq * 4];
                f32x4 a1 = *(const f32x4*)&a_s[2 * np + 1][dq * 4];
                l0 += a0.x * kr[dq * 4] + a0.y * kr[dq * 4 + 1] + a0.z * kr[dq * 4 + 2] + a0.w * kr[dq * 4 + 3];
                l1 += a1.x * kr[dq * 4] + a1.y * kr[dq * 4 + 1] + a1.z * kr[dq * 4 + 2] + a1.w * kr[dq * 4 + 3];
            }
            uint32_t e2 = (uint32_t)f2b(__expf(l0)) | ((uint32_t)f2b(__expf(l1)) << 16);
            *(uint32_t*)&EL[t][2 * np] = e2;
        }
        __syncthreads();
#pragma unroll 1
        for (int tt = 0; tt < 256; ++tt) {
            float e = b2f(EL[tt][n_own]);
            if (dl == 0) s_acc += e;
            ushort4 va = *(const ushort4*)&vL[tt][dl * 8];
            ushort4 vbx = *(const ushort4*)&vL[tt][dl * 8 + 4];
            accr[0] += e * b2f(va.x);
            accr[1] += e * b2f(va.y);
            accr[2] += e * b2f(va.z);
            accr[3] += e * b2f(va.w);
            accr[4] += e * b2f(vbx.x);
            accr[5] += e * b2f(vbx.y);
            accr[6] += e * b2f(vbx.z);
            accr[7] += e * b2f(vbx.w);
        }
        __syncthreads();
    }
#pragma unroll
    for (int i = 0; i < 8; ++i)
        atomicAdd(&attn_g[(((size_t)b * 8 + h) * 64 + n_own) * 32 + dl * 8 + i], accr[i]);
    if (dl == 0) atomicAdd(&s_g[((size_t)b * 8 + h) * 64 + n_own], s_acc);
}

// ---------------- K6: stage-2 attention (queries attend to agents) ----------------
__global__ __launch_bounds__(256) void k_att2(const float* __restrict__ qkv, const float* __restrict__ ap,
                                              const float* __restrict__ attn_g, const float* __restrict__ s_g,
                                              float* __restrict__ outp) {
    const int bid = blockIdx.x;
    const int ch = bid & 15, h = (bid >> 4) & 7, b = bid >> 7;
    const int t = threadIdx.x;
    __shared__ float a2[64][36];
    __shared__ float at2[64][36];
    __shared__ float sInv[64];
#pragma unroll
    for (int i = 0; i < 8; ++i) {
        int idx = i * 256 + t;
        int n = idx & 63, d = idx >> 6;
        a2[n][d] = ap[((size_t)b * 256 + h * 32 + d) * 64 + n] * SCALE;
    }
    if (t < 64) sInv[t] = 1.0f / s_g[((size_t)b * 8 + h) * 64 + t];
    __syncthreads();
#pragma unroll
    for (int i = 0; i < 8; ++i) {
        int idx = i * 256 + t;
        int n = idx >> 5, d = idx & 31;
        at2[n][d] = attn_g[(((size_t)b * 8 + h) * 64 + n) * 32 + d] * sInv[n];
    }
    __syncthreads();
    const float* qb = qkv + ((size_t)b * 768 + h * 32) * 4096;
    int pix = ch * 256 + t;
    float qr[32];
#pragma unroll
    for (int d = 0; d < 32; ++d) qr[d] = qb[(size_t)d * 4096 + pix];
    float oacc[32] = {};
    float s = 0.f;
#pragma unroll 1
    for (int n = 0; n < 64; ++n) {
        float l = 0;
#pragma unroll
        for (int dq = 0; dq < 8; ++dq) {
            f32x4 av = *(const f32x4*)&a2[n][dq * 4];
            l += av.x * qr[dq * 4] + av.y * qr[dq * 4 + 1] + av.z * qr[dq * 4 + 2] + av.w * qr[dq * 4 + 3];
        }
        float e = __expf(l);
        s += e;
#pragma unroll
        for (int dq = 0; dq < 8; ++dq) {
            f32x4 tv = *(const f32x4*)&at2[n][dq * 4];
            oacc[dq * 4] += e * tv.x;
            oacc[dq * 4 + 1] += e * tv.y;
            oacc[dq * 4 + 2] += e * tv.z;
            oacc[dq * 4 + 3] += e * tv.w;
        }
    }
    float si = 1.0f / s;
#pragma unroll
    for (int d = 0; d < 32; ++d)
        outp[((size_t)b * 256 + h * 32 + d) * 4096 + pix] = oacc[d] * si;
}

// ---------------- K7: depthwise 3x3 PE on v, added into outp ----------------
__global__ __launch_bounds__(256) void k_pe(const float* __restrict__ qkv, const float* __restrict__ pw,
                                            const float* __restrict__ ps, const float* __restrict__ pbias,
                                            float* __restrict__ outp) {
    int gid = blockIdx.x * 256 + threadIdx.x;
    int x = gid & 63, y = (gid >> 6) & 63, c = (gid >> 12) & 255, b = gid >> 20;
    const float* vp = qkv + ((size_t)b * 768 + 512 + c) * 4096;
    const float* wp = pw + c * 9;
    float sum = 0;
#pragma unroll
    for (int ky = 0; ky < 3; ++ky) {
        int yy = y + ky - 1;
        if ((unsigned)yy >= 64u) continue;
#pragma unroll
        for (int kx = 0; kx < 3; ++kx) {
            int xx = x + kx - 1;
            if ((unsigned)xx >= 64u) continue;
            sum += vp[yy * 64 + xx] * wp[ky * 3 + kx];
        }
    }
    outp[gid] += ps[c] * sum + pbias[c];
}

// ---------------- K8: 1x1 projection ----------------
__global__ __launch_bounds__(256) void k_proj(const float* __restrict__ outp, const float* __restrict__ pwT,
                                              const float* __restrict__ pbias, float* __restrict__ out) {
    const int bid = blockIdx.x;
    const int pblk = bid & 127, b = bid >> 7;
    const int p0 = pblk * 32;
    const int t = threadIdx.x;
    __shared__ float X[256][32];
    __shared__ float OT[256][33];
#pragma unroll
    for (int i = 0; i < 32; ++i) {
        int idx = i * 256 + t;
        int c = idx >> 5, p = idx & 31;
        X[c][p] = outp[((size_t)b * 256 + c) * 4096 + p0 + p];
    }
    __syncthreads();
    float acc[32] = {};
#pragma unroll 1
    for (int c = 0; c < 256; ++c) {
        float wv = pwT[(size_t)c * 256 + t];
#pragma unroll
        for (int pq = 0; pq < 8; ++pq) {
            f32x4 xv = *(const f32x4*)&X[c][pq * 4];
            acc[pq * 4] += wv * xv.x;
            acc[pq * 4 + 1] += wv * xv.y;
            acc[pq * 4 + 2] += wv * xv.z;
            acc[pq * 4 + 3] += wv * xv.w;
        }
    }
    float bb = pbias[t];
#pragma unroll
    for (int p = 0; p < 32; ++p) OT[t][p] = acc[p] + bb;
    __syncthreads();
#pragma unroll
    for (int i = 0; i < 32; ++i) {
        int idx = i * 256 + t;
        int o = idx >> 5, p = idx & 31;
        out[((size_t)b * 256 + o) * 4096 + p0 + p] = OT[o][p];
    }
}

extern "C" void kernel_launch(void* const* d_in, const int* in_sizes, int n_in,
                              void* d_out, int out_size, void* d_ws, size_t ws_size,
                              hipStream_t stream) {
    const float* x = (const float*)d_in[0];
    const float* qkv_w = (const float*)d_in[1];
    const float* qkv_s = (const float*)d_in[2];
    const float* qkv_b = (const float*)d_in[3];
    const float* pe_w = (const float*)d_in[4];
    const float* pe_s = (const float*)d_in[5];
    const float* pe_b = (const float*)d_in[6];
    const float* proj_w = (const float*)d_in[7];
    const float* proj_s = (const float*)d_in[8];
    const float* proj_b = (const float*)d_in[9];
    float* out = (float*)d_out;

    char* ws = (char*)d_ws;
    ushort* xp = (ushort*)(ws);                  // 17,842,176 B : padded NHWC bf16 input
    ushort* Wa = (ushort*)(ws + 17842176);       //  3,538,944 B : folded qkv weights bf16
    float* qkv = (float*)(ws + 21381120);        // 100,663,296 B: qkv activations f32
    float* apool = (float*)(ws + 122044416);     //    524,288 B : agent tokens
    float* attn_g = (float*)(ws + 122568704);    //    524,288 B : stage-1 partial numerators
    float* s_g = (float*)(ws + 123092992);       //     16,384 B : stage-1 partial denominators
    float* outp = (float*)(ws + 123109376);      // 33,554,432 B : pre-projection output
    float* pwT = (float*)(ws + 156663808);       //    262,144 B : folded proj weights^T

    hipMemsetAsync(xp, 0, 17842176, stream);
    hipMemsetAsync(attn_g, 0, 524288 + 16384, stream);
    k_pad<<<512, 256, 0, stream>>>(x, xp);
    k_foldw<<<768, 256, 0, stream>>>(qkv_w, qkv_s, Wa);
    k_foldp<<<256, 256, 0, stream>>>(proj_w, proj_s, pwT);
    k_conv<<<1536, 256, 0, stream>>>(xp, Wa, qkv_b, qkv);
    k_pool<<<512, 256, 0, stream>>>(qkv, apool);
    k_att1<<<256, 256, 0, stream>>>(qkv, apool, attn_g, s_g);
    k_att2<<<1024, 256, 0, stream>>>(qkv, apool, attn_g, s_g, outp);
    k_pe<<<32768, 256, 0, stream>>>(qkv, pe_w, pe_s, pe_b, outp);
    k_proj<<<1024, 256, 0, stream>>>(outp, pwT, proj_b, out);
}

// Round 2
// 451.797 us; speedup vs baseline: 1.4272x; 1.4272x over previous
//
#include <hip/hip_runtime.h>
#include <cstdint>

typedef __attribute__((ext_vector_type(8))) short short8;
typedef __attribute__((ext_vector_type(4))) float f32x4;

#define THETA 0.7f
#define SCALE 0.17677669529663687f

__device__ __forceinline__ ushort f2b(float f) {
    uint32_t u = __float_as_uint(f);
    u += 0x7FFFu + ((u >> 16) & 1u);
    return (ushort)(u >> 16);
}
__device__ __forceinline__ float b2f(ushort b) {
    return __uint_as_float(((uint32_t)b) << 16);
}

// ---------------- K1: pad + cast + NCHW->NHWC transpose ----------------
__global__ __launch_bounds__(256) void k_pad(const float* __restrict__ x, ushort* __restrict__ xp) {
    int b = blockIdx.x >> 6, y = blockIdx.x & 63;
    int t = threadIdx.x;
    __shared__ float buf[64][65];
    for (int cc = 0; cc < 4; ++cc) {
        __syncthreads();
#pragma unroll
        for (int i = 0; i < 16; ++i) {
            int idx = i * 256 + t;
            int c = idx >> 6, xx = idx & 63;
            buf[c][xx] = x[(((size_t)b * 256 + cc * 64 + c) << 12) + (y << 6) + xx];
        }
        __syncthreads();
#pragma unroll
        for (int i = 0; i < 16; ++i) {
            int idx = i * 256 + t;
            int xx = idx >> 6, c = idx & 63;
            xp[((size_t)(b * 66 + y + 1) * 66 + (xx + 1)) * 256 + cc * 64 + c] = f2b(buf[c][xx]);
        }
    }
}

// ---------------- K2a: fold qkv weights ----------------
__global__ __launch_bounds__(256) void k_foldw(const float* __restrict__ w, const float* __restrict__ s,
                                               ushort* __restrict__ Wa) {
    int o = blockIdx.x, c = threadIdx.x;
    const float* wp = w + ((size_t)o * 256 + c) * 9;
    float v[9];
#pragma unroll
    for (int p = 0; p < 9; ++p) v[p] = wp[p];
    float hv = v[1] + v[3] + v[4] + v[5] + v[7];
    v[4] -= THETA * hv;
    float sc = s[o];
#pragma unroll
    for (int p = 0; p < 9; ++p)
        Wa[(size_t)o * 2304 + p * 256 + c] = f2b(v[p] * sc);
}

// ---------------- K2b: fold proj weights, hi/lo bf16 split, [o][c] ----------------
__global__ __launch_bounds__(256) void k_foldp(const float* __restrict__ w, const float* __restrict__ s,
                                               ushort* __restrict__ Wh, ushort* __restrict__ Wl) {
    int o = blockIdx.x, c = threadIdx.x;
    float v = w[(size_t)o * 256 + c] * s[o];
    ushort hi = f2b(v);
    Wh[(size_t)o * 256 + c] = hi;
    Wl[(size_t)o * 256 + c] = f2b(v - b2f(hi));
}

// ---------------- K3: qkv conv as implicit-im2col bf16 MFMA GEMM ----------------
__global__ __launch_bounds__(256) void k_conv(const ushort* __restrict__ xp, const ushort* __restrict__ Wa,
                                              const float* __restrict__ qbias, float* __restrict__ qkv) {
    __shared__ ushort Al[128][40];
    __shared__ ushort Bl[128][40];
    const int t = threadIdx.x;
    const int bid0 = blockIdx.x;
    const int bid = (bid0 & 7) * 192 + (bid0 >> 3);  // XCD swizzle: one batch per XCD
    const int b = bid / 192;
    const int ob = (bid % 192) >> 5;
    const int pb = bid & 31;
    const int o0 = ob << 7;
    const int lane = t & 63;
    const int w = t >> 6;
    const int rw = t >> 2;
    const int q4 = t & 3;
    const ushort* Ag0 = Wa + (size_t)(o0 + rw) * 2304 + q4 * 8;
    const ushort* Ag1 = Ag0 + (size_t)64 * 2304;
    const int y0 = pb * 2;
    const size_t xb = (size_t)b * 66 * 66 * 256;

    f32x4 acc[4][4] = {};

    const int ow2 = (w >> 1) << 6;
    const int pw2 = (w & 1) << 6;
    const int fr = lane & 15;
    const int fs = (lane >> 4) << 3;

    uint4 ra0, ra1, rb0, rb1;
    auto loadk = [&](int kn) {
        int pp = kn >> 3;
        int c0 = (kn & 7) << 5;
        int ky = pp / 3, kx = pp - ky * 3;
        ra0 = *(const uint4*)(Ag0 + kn * 32);
        ra1 = *(const uint4*)(Ag1 + kn * 32);
        const ushort* bp = xp + xb + ((size_t)((y0 + ky) * 66 + (rw + kx))) * 256 + c0 + q4 * 8;
        rb0 = *(const uint4*)bp;
        rb1 = *(const uint4*)(bp + 66 * 256);
    };
    loadk(0);
    for (int kc = 0; kc < 72; ++kc) {
        if (kc) __syncthreads();
        *(uint4*)&Al[rw][q4 * 8] = ra0;
        *(uint4*)&Al[rw + 64][q4 * 8] = ra1;
        *(uint4*)&Bl[rw][q4 * 8] = rb0;
        *(uint4*)&Bl[rw + 64][q4 * 8] = rb1;
        __syncthreads();
        if (kc < 71) loadk(kc + 1);
        short8 af[4], bf[4];
#pragma unroll
        for (int i = 0; i < 4; ++i) af[i] = *(const short8*)&Al[ow2 + i * 16 + fr][fs];
#pragma unroll
        for (int j = 0; j < 4; ++j) bf[j] = *(const short8*)&Bl[pw2 + j * 16 + fr][fs];
#pragma unroll
        for (int i = 0; i < 4; ++i)
#pragma unroll
            for (int j = 0; j < 4; ++j)
                acc[i][j] = __builtin_amdgcn_mfma_f32_16x16x32_bf16(af[i], bf[j], acc[i][j], 0, 0, 0);
    }
    const int pbase = pb * 128 + pw2 + (lane & 15);
#pragma unroll
    for (int i = 0; i < 4; ++i) {
        int o = o0 + ow2 + i * 16 + (lane >> 4) * 4;
#pragma unroll
        for (int r = 0; r < 4; ++r) {
            float bias = qbias[o + r];
            float* dst = qkv + ((size_t)b * 768 + o + r) * 4096 + pbase;
#pragma unroll
            for (int j = 0; j < 4; ++j)
                dst[j * 16] = acc[i][j][r] + bias;
        }
    }
}

// ---------------- K4: agent pooling, coalesced ----------------
__global__ __launch_bounds__(256) void k_pool(const float* __restrict__ qkv, float* __restrict__ ap) {
    const int bid = blockIdx.x;
    const int b = bid >> 8, c = bid & 255;
    const int t = threadIdx.x;
    const int y = t >> 2, xq = t & 3;
    __shared__ float lp[64][8];
    const float* qp = qkv + ((size_t)b * 768 + c) * 4096 + y * 64 + xq * 16;
    f32x4 v0 = *(const f32x4*)(qp);
    f32x4 v1 = *(const f32x4*)(qp + 4);
    f32x4 v2 = *(const f32x4*)(qp + 8);
    f32x4 v3 = *(const f32x4*)(qp + 12);
    lp[y][xq * 2] = v0.x + v0.y + v0.z + v0.w + v1.x + v1.y + v1.z + v1.w;
    lp[y][xq * 2 + 1] = v2.x + v2.y + v2.z + v2.w + v3.x + v3.y + v3.z + v3.w;
    __syncthreads();
    if (t < 64) {
        int py = t >> 3, px = t & 7;
        float s = 0;
#pragma unroll
        for (int r = 0; r < 8; ++r) s += lp[py * 8 + r][px];
        ap[((size_t)b * 256 + c) * 64 + t] = s * (1.0f / 64.0f);
    }
}

// ---------------- K5: stage-1 attention partials ----------------
__global__ __launch_bounds__(256) void k_att1(const float* __restrict__ qkv, const float* __restrict__ ap,
                                              float* __restrict__ attn_g, float* __restrict__ s_g) {
    const int bid0 = blockIdx.x;
    const int bid = (bid0 & 7) * 64 + (bid0 >> 3);
    const int seg = bid & 7, h = (bid >> 3) & 7, b = bid >> 6;
    const int t = threadIdx.x;
    __shared__ float a_s[64][36];
    __shared__ ushort EL[256][68];
    __shared__ ushort vL[256][40];
#pragma unroll
    for (int i = 0; i < 8; ++i) {
        int idx = i * 256 + t;
        int n = idx & 63, d = idx >> 6;
        a_s[n][d] = ap[((size_t)b * 256 + h * 32 + d) * 64 + n] * SCALE;
    }
    const float* kb = qkv + ((size_t)b * 768 + 256 + h * 32) * 4096;
    const float* vb = qkv + ((size_t)b * 768 + 512 + h * 32) * 4096;
    const int n_own = t >> 2;
    const int dl = t & 3;
    float accr[8] = {0, 0, 0, 0, 0, 0, 0, 0};
    float s_acc = 0.f;
    __syncthreads();
    for (int chunk = 0; chunk < 2; ++chunk) {
        int pix = (seg * 2 + chunk) * 256 + t;
        float kr[32];
#pragma unroll
        for (int d = 0; d < 32; ++d) kr[d] = kb[(size_t)d * 4096 + pix];
#pragma unroll
        for (int i = 0; i < 4; ++i) {
            uint4 pk;
            pk.x = (uint32_t)f2b(vb[(size_t)(8 * i + 0) * 4096 + pix]) |
                   ((uint32_t)f2b(vb[(size_t)(8 * i + 1) * 4096 + pix]) << 16);
            pk.y = (uint32_t)f2b(vb[(size_t)(8 * i + 2) * 4096 + pix]) |
                   ((uint32_t)f2b(vb[(size_t)(8 * i + 3) * 4096 + pix]) << 16);
            pk.z = (uint32_t)f2b(vb[(size_t)(8 * i + 4) * 4096 + pix]) |
                   ((uint32_t)f2b(vb[(size_t)(8 * i + 5) * 4096 + pix]) << 16);
            pk.w = (uint32_t)f2b(vb[(size_t)(8 * i + 6) * 4096 + pix]) |
                   ((uint32_t)f2b(vb[(size_t)(8 * i + 7) * 4096 + pix]) << 16);
            *(uint4*)&vL[t][i * 8] = pk;
        }
#pragma unroll 1
        for (int np = 0; np < 32; ++np) {
            float l0 = 0, l1 = 0;
#pragma unroll
            for (int dq = 0; dq < 8; ++dq) {
                f32x4 a0 = *(const f32x4*)&a_s[2 * np][dq * 4];
                f32x4 a1 = *(const f32x4*)&a_s[2 * np + 1][dq * 4];
                l0 += a0.x * kr[dq * 4] + a0.y * kr[dq * 4 + 1] + a0.z * kr[dq * 4 + 2] + a0.w * kr[dq * 4 + 3];
                l1 += a1.x * kr[dq * 4] + a1.y * kr[dq * 4 + 1] + a1.z * kr[dq * 4 + 2] + a1.w * kr[dq * 4 + 3];
            }
            uint32_t e2 = (uint32_t)f2b(__expf(l0)) | ((uint32_t)f2b(__expf(l1)) << 16);
            *(uint32_t*)&EL[t][2 * np] = e2;
        }
        __syncthreads();
#pragma unroll 1
        for (int tt = 0; tt < 256; ++tt) {
            float e = b2f(EL[tt][n_own]);
            if (dl == 0) s_acc += e;
            ushort4 va = *(const ushort4*)&vL[tt][dl * 8];
            ushort4 vbx = *(const ushort4*)&vL[tt][dl * 8 + 4];
            accr[0] += e * b2f(va.x);
            accr[1] += e * b2f(va.y);
            accr[2] += e * b2f(va.z);
            accr[3] += e * b2f(va.w);
            accr[4] += e * b2f(vbx.x);
            accr[5] += e * b2f(vbx.y);
            accr[6] += e * b2f(vbx.z);
            accr[7] += e * b2f(vbx.w);
        }
        __syncthreads();
    }
#pragma unroll
    for (int i = 0; i < 8; ++i)
        atomicAdd(&attn_g[(((size_t)b * 8 + h) * 64 + n_own) * 32 + dl * 8 + i], accr[i]);
    if (dl == 0) atomicAdd(&s_g[((size_t)b * 8 + h) * 64 + n_own], s_acc);
}

// ---------------- K6: stage-2 attention ----------------
__global__ __launch_bounds__(256) void k_att2(const float* __restrict__ qkv, const float* __restrict__ ap,
                                              const float* __restrict__ attn_g, const float* __restrict__ s_g,
                                              float* __restrict__ outp) {
    const int bid0 = blockIdx.x;
    const int bid = (bid0 & 7) * 128 + (bid0 >> 3);
    const int ch = bid & 15, h = (bid >> 4) & 7, b = bid >> 7;
    const int t = threadIdx.x;
    __shared__ float a2[64][36];
    __shared__ float at2[64][36];
    __shared__ float sInv[64];
#pragma unroll
    for (int i = 0; i < 8; ++i) {
        int idx = i * 256 + t;
        int n = idx & 63, d = idx >> 6;
        a2[n][d] = ap[((size_t)b * 256 + h * 32 + d) * 64 + n] * SCALE;
    }
    if (t < 64) sInv[t] = 1.0f / s_g[((size_t)b * 8 + h) * 64 + t];
    __syncthreads();
#pragma unroll
    for (int i = 0; i < 8; ++i) {
        int idx = i * 256 + t;
        int n = idx >> 5, d = idx & 31;
        at2[n][d] = attn_g[(((size_t)b * 8 + h) * 64 + n) * 32 + d] * sInv[n];
    }
    __syncthreads();
    const float* qb = qkv + ((size_t)b * 768 + h * 32) * 4096;
    int pix = ch * 256 + t;
    float qr[32];
#pragma unroll
    for (int d = 0; d < 32; ++d) qr[d] = qb[(size_t)d * 4096 + pix];
    float oacc[32] = {};
    float s = 0.f;
#pragma unroll 1
    for (int n = 0; n < 64; ++n) {
        float l = 0;
#pragma unroll
        for (int dq = 0; dq < 8; ++dq) {
            f32x4 av = *(const f32x4*)&a2[n][dq * 4];
            l += av.x * qr[dq * 4] + av.y * qr[dq * 4 + 1] + av.z * qr[dq * 4 + 2] + av.w * qr[dq * 4 + 3];
        }
        float e = __expf(l);
        s += e;
#pragma unroll
        for (int dq = 0; dq < 8; ++dq) {
            f32x4 tv = *(const f32x4*)&at2[n][dq * 4];
            oacc[dq * 4] += e * tv.x;
            oacc[dq * 4 + 1] += e * tv.y;
            oacc[dq * 4 + 2] += e * tv.z;
            oacc[dq * 4 + 3] += e * tv.w;
        }
    }
    float si = 1.0f / s;
#pragma unroll
    for (int d = 0; d < 32; ++d)
        outp[((size_t)b * 256 + h * 32 + d) * 4096 + pix] = oacc[d] * si;
}

// ---------------- K7: depthwise 3x3 PE on v, vectorized x4 ----------------
__global__ __launch_bounds__(256) void k_pe(const float* __restrict__ qkv, const float* __restrict__ pw,
                                            const float* __restrict__ ps, const float* __restrict__ pbias,
                                            float* __restrict__ outp) {
    int gid = blockIdx.x * 256 + threadIdx.x;  // [0, 2^21)
    int x4 = (gid & 15) << 2;
    int y = (gid >> 4) & 63;
    int c = (gid >> 10) & 255;
    int b = gid >> 18;
    const float* vp = qkv + ((size_t)b * 768 + 512 + c) * 4096;
    const float* wp = pw + c * 9;
    float s0 = 0, s1 = 0, s2 = 0, s3 = 0;
#pragma unroll
    for (int ky = 0; ky < 3; ++ky) {
        int yy = y + ky - 1;
        if ((unsigned)yy >= 64u) continue;
        const float* rp = vp + yy * 64 + x4;
        f32x4 m = *(const f32x4*)rp;
        float lft = (x4 > 0) ? rp[-1] : 0.f;
        float rgt = (x4 < 60) ? rp[4] : 0.f;
        float w0 = wp[ky * 3], w1 = wp[ky * 3 + 1], w2 = wp[ky * 3 + 2];
        s0 += w0 * lft + w1 * m.x + w2 * m.y;
        s1 += w0 * m.x + w1 * m.y + w2 * m.z;
        s2 += w0 * m.y + w1 * m.z + w2 * m.w;
        s3 += w0 * m.z + w1 * m.w + w2 * rgt;
    }
    float sc = ps[c], bb = pbias[c];
    float* op = outp + ((size_t)b * 256 + c) * 4096 + y * 64 + x4;
    f32x4 o = *(const f32x4*)op;
    o.x += sc * s0 + bb;
    o.y += sc * s1 + bb;
    o.z += sc * s2 + bb;
    o.w += sc * s3 + bb;
    *(f32x4*)op = o;
}

// ---------------- K8: 1x1 projection as bf16 MFMA GEMM (hi/lo weights) ----------------
// out[o][pix] = sum_c (Wh+Wl)[o][c] * outp[c][pix] + proj_b[o]
__global__ __launch_bounds__(256) void k_proj(const float* __restrict__ outp, const ushort* __restrict__ Wh,
                                              const ushort* __restrict__ Wl, const float* __restrict__ pbias,
                                              float* __restrict__ out) {
    __shared__ ushort Ah[128][40];
    __shared__ ushort Alo[128][40];
    __shared__ ushort Xl[32][132];
    const int t = threadIdx.x;
    const int bid0 = blockIdx.x;
    const int bid = (bid0 & 7) * 64 + (bid0 >> 3);  // one batch per XCD
    const int b = bid >> 6;
    const int ob = (bid >> 5) & 1;
    const int pb = bid & 31;
    const int o0 = ob << 7;
    const int p0 = pb << 7;
    const int lane = t & 63;
    const int w = t >> 6;
    const int rw = t >> 2, q4 = t & 3;       // A staging map
    const int cl = t >> 3, pg = t & 7;       // B staging map
    const int ow2 = (w >> 1) << 6;
    const int pw2 = (w & 1) << 6;
    const int fr = lane & 15;
    const int fs = (lane >> 4) << 3;

    f32x4 acc[4][4] = {};
    uint4 rah0, rah1, ral0, ral1;
    f32x4 rx[4];
    auto loadk = [&](int kc) {
        const size_t awoff = (size_t)(o0 + rw) * 256 + kc * 32 + q4 * 8;
        rah0 = *(const uint4*)(Wh + awoff);
        rah1 = *(const uint4*)(Wh + awoff + (size_t)64 * 256);
        ral0 = *(const uint4*)(Wl + awoff);
        ral1 = *(const uint4*)(Wl + awoff + (size_t)64 * 256);
        const float* xsrc = outp + ((size_t)b * 256 + kc * 32 + cl) * 4096 + p0 + pg * 16;
#pragma unroll
        for (int m = 0; m < 4; ++m) rx[m] = *(const f32x4*)(xsrc + m * 4);
    };
    loadk(0);
    for (int kc = 0; kc < 8; ++kc) {
        if (kc) __syncthreads();
        *(uint4*)&Ah[rw][q4 * 8] = rah0;
        *(uint4*)&Ah[rw + 64][q4 * 8] = rah1;
        *(uint4*)&Alo[rw][q4 * 8] = ral0;
        *(uint4*)&Alo[rw + 64][q4 * 8] = ral1;
#pragma unroll
        for (int m = 0; m < 4; ++m) {
            ushort4 u;
            u.x = f2b(rx[m].x);
            u.y = f2b(rx[m].y);
            u.z = f2b(rx[m].z);
            u.w = f2b(rx[m].w);
            *(ushort4*)&Xl[cl][pg * 16 + m * 4] = u;
        }
        __syncthreads();
        if (kc < 7) loadk(kc + 1);
        short8 ah[4], al[4], bf[4];
#pragma unroll
        for (int i = 0; i < 4; ++i) {
            ah[i] = *(const short8*)&Ah[ow2 + i * 16 + fr][fs];
            al[i] = *(const short8*)&Alo[ow2 + i * 16 + fr][fs];
        }
#pragma unroll
        for (int j = 0; j < 4; ++j) {
            int pl = pw2 + j * 16 + fr;
#pragma unroll
            for (int kk = 0; kk < 8; ++kk) bf[j][kk] = (short)Xl[fs + kk][pl];
        }
#pragma unroll
        for (int i = 0; i < 4; ++i)
#pragma unroll
            for (int j = 0; j < 4; ++j) {
                acc[i][j] = __builtin_amdgcn_mfma_f32_16x16x32_bf16(ah[i], bf[j], acc[i][j], 0, 0, 0);
                acc[i][j] = __builtin_amdgcn_mfma_f32_16x16x32_bf16(al[i], bf[j], acc[i][j], 0, 0, 0);
            }
    }
    const int pbase = p0 + pw2 + (lane & 15);
#pragma unroll
    for (int i = 0; i < 4; ++i) {
        int o = o0 + ow2 + i * 16 + (lane >> 4) * 4;
#pragma unroll
        for (int r = 0; r < 4; ++r) {
            float bias = pbias[o + r];
            float* dst = out + ((size_t)b * 256 + o + r) * 4096 + pbase;
#pragma unroll
            for (int j = 0; j < 4; ++j)
                dst[j * 16] = acc[i][j][r] + bias;
        }
    }
}

extern "C" void kernel_launch(void* const* d_in, const int* in_sizes, int n_in,
                              void* d_out, int out_size, void* d_ws, size_t ws_size,
                              hipStream_t stream) {
    const float* x = (const float*)d_in[0];
    const float* qkv_w = (const float*)d_in[1];
    const float* qkv_s = (const float*)d_in[2];
    const float* qkv_b = (const float*)d_in[3];
    const float* pe_w = (const float*)d_in[4];
    const float* pe_s = (const float*)d_in[5];
    const float* pe_b = (const float*)d_in[6];
    const float* proj_w = (const float*)d_in[7];
    const float* proj_s = (const float*)d_in[8];
    const float* proj_b = (const float*)d_in[9];
    float* out = (float*)d_out;

    char* ws = (char*)d_ws;
    ushort* xp = (ushort*)(ws);                  // 17,842,176 B
    ushort* Wa = (ushort*)(ws + 17842176);       //  3,538,944 B
    float* qkv = (float*)(ws + 21381120);        // 100,663,296 B
    float* apool = (float*)(ws + 122044416);     //    524,288 B
    float* attn_g = (float*)(ws + 122568704);    //    524,288 B
    float* s_g = (float*)(ws + 123092992);       //     16,384 B
    float* outp = (float*)(ws + 123109376);      // 33,554,432 B
    ushort* Wh = (ushort*)(ws + 156663808);      //    131,072 B
    ushort* Wl = (ushort*)(ws + 156794880);      //    131,072 B

    hipMemsetAsync(xp, 0, 17842176, stream);
    hipMemsetAsync(attn_g, 0, 524288 + 16384, stream);
    k_pad<<<512, 256, 0, stream>>>(x, xp);
    k_foldw<<<768, 256, 0, stream>>>(qkv_w, qkv_s, Wa);
    k_foldp<<<256, 256, 0, stream>>>(proj_w, proj_s, Wh, Wl);
    k_conv<<<1536, 256, 0, stream>>>(xp, Wa, qkv_b, qkv);
    k_pool<<<2048, 256, 0, stream>>>(qkv, apool);
    k_att1<<<512, 256, 0, stream>>>(qkv, apool, attn_g, s_g);
    k_att2<<<1024, 256, 0, stream>>>(qkv, apool, attn_g, s_g, outp);
    k_pe<<<8192, 256, 0, stream>>>(qkv, pe_w, pe_s, pe_b, outp);
    k_proj<<<512, 256, 0, stream>>>(outp, Wh, Wl, proj_b, out);
}

// Round 3
// 432.210 us; speedup vs baseline: 1.4919x; 1.0453x over previous
//
#include <hip/hip_runtime.h>
#include <cstdint>

typedef __attribute__((ext_vector_type(8))) short short8;
typedef __attribute__((ext_vector_type(4))) float f32x4;

#define THETA 0.7f
#define SCALE 0.17677669529663687f

__device__ __forceinline__ ushort f2b(float f) {
    uint32_t u = __float_as_uint(f);
    u += 0x7FFFu + ((u >> 16) & 1u);
    return (ushort)(u >> 16);
}
__device__ __forceinline__ float b2f(ushort b) {
    return __uint_as_float(((uint32_t)b) << 16);
}

// ---------------- K1: pad + cast + NCHW->NHWC transpose ----------------
__global__ __launch_bounds__(256) void k_pad(const float* __restrict__ x, ushort* __restrict__ xp) {
    int b = blockIdx.x >> 6, y = blockIdx.x & 63;
    int t = threadIdx.x;
    __shared__ float buf[64][65];
    for (int cc = 0; cc < 4; ++cc) {
        __syncthreads();
#pragma unroll
        for (int i = 0; i < 16; ++i) {
            int idx = i * 256 + t;
            int c = idx >> 6, xx = idx & 63;
            buf[c][xx] = x[(((size_t)b * 256 + cc * 64 + c) << 12) + (y << 6) + xx];
        }
        __syncthreads();
#pragma unroll
        for (int i = 0; i < 16; ++i) {
            int idx = i * 256 + t;
            int xx = idx >> 6, c = idx & 63;
            xp[((size_t)(b * 66 + y + 1) * 66 + (xx + 1)) * 256 + cc * 64 + c] = f2b(buf[c][xx]);
        }
    }
}

// ---------------- K2a: fold qkv weights ----------------
__global__ __launch_bounds__(256) void k_foldw(const float* __restrict__ w, const float* __restrict__ s,
                                               ushort* __restrict__ Wa) {
    int o = blockIdx.x, c = threadIdx.x;
    const float* wp = w + ((size_t)o * 256 + c) * 9;
    float v[9];
#pragma unroll
    for (int p = 0; p < 9; ++p) v[p] = wp[p];
    float hv = v[1] + v[3] + v[4] + v[5] + v[7];
    v[4] -= THETA * hv;
    float sc = s[o];
#pragma unroll
    for (int p = 0; p < 9; ++p)
        Wa[(size_t)o * 2304 + p * 256 + c] = f2b(v[p] * sc);
}

// ---------------- K2b: fold proj weights, hi/lo bf16 split, [o][c] ----------------
__global__ __launch_bounds__(256) void k_foldp(const float* __restrict__ w, const float* __restrict__ s,
                                               ushort* __restrict__ Wh, ushort* __restrict__ Wl) {
    int o = blockIdx.x, c = threadIdx.x;
    float v = w[(size_t)o * 256 + c] * s[o];
    ushort hi = f2b(v);
    Wh[(size_t)o * 256 + c] = hi;
    Wl[(size_t)o * 256 + c] = f2b(v - b2f(hi));
}

// ---------------- K3: qkv conv as implicit-im2col bf16 MFMA GEMM, bf16 out ----------------
__global__ __launch_bounds__(256) void k_conv(const ushort* __restrict__ xp, const ushort* __restrict__ Wa,
                                              const float* __restrict__ qbias, ushort* __restrict__ qkv) {
    __shared__ ushort Al[128][40];
    __shared__ ushort Bl[128][40];
    const int t = threadIdx.x;
    const int bid0 = blockIdx.x;
    const int bid = (bid0 & 7) * 192 + (bid0 >> 3);  // XCD swizzle: one batch per XCD
    const int b = bid / 192;
    const int ob = (bid % 192) >> 5;
    const int pb = bid & 31;
    const int o0 = ob << 7;
    const int lane = t & 63;
    const int w = t >> 6;
    const int rw = t >> 2;
    const int q4 = t & 3;
    const ushort* Ag0 = Wa + (size_t)(o0 + rw) * 2304 + q4 * 8;
    const ushort* Ag1 = Ag0 + (size_t)64 * 2304;
    const int y0 = pb * 2;
    const size_t xb = (size_t)b * 66 * 66 * 256;

    f32x4 acc[4][4] = {};

    const int ow2 = (w >> 1) << 6;
    const int pw2 = (w & 1) << 6;
    const int fr = lane & 15;
    const int fs = (lane >> 4) << 3;

    uint4 ra0, ra1, rb0, rb1;
    auto loadk = [&](int kn) {
        int pp = kn >> 3;
        int c0 = (kn & 7) << 5;
        int ky = pp / 3, kx = pp - ky * 3;
        ra0 = *(const uint4*)(Ag0 + kn * 32);
        ra1 = *(const uint4*)(Ag1 + kn * 32);
        const ushort* bp = xp + xb + ((size_t)((y0 + ky) * 66 + (rw + kx))) * 256 + c0 + q4 * 8;
        rb0 = *(const uint4*)bp;
        rb1 = *(const uint4*)(bp + 66 * 256);
    };
    loadk(0);
    for (int kc = 0; kc < 72; ++kc) {
        if (kc) __syncthreads();
        *(uint4*)&Al[rw][q4 * 8] = ra0;
        *(uint4*)&Al[rw + 64][q4 * 8] = ra1;
        *(uint4*)&Bl[rw][q4 * 8] = rb0;
        *(uint4*)&Bl[rw + 64][q4 * 8] = rb1;
        __syncthreads();
        if (kc < 71) loadk(kc + 1);
        short8 af[4], bf[4];
#pragma unroll
        for (int i = 0; i < 4; ++i) af[i] = *(const short8*)&Al[ow2 + i * 16 + fr][fs];
#pragma unroll
        for (int j = 0; j < 4; ++j) bf[j] = *(const short8*)&Bl[pw2 + j * 16 + fr][fs];
#pragma unroll
        for (int i = 0; i < 4; ++i)
#pragma unroll
            for (int j = 0; j < 4; ++j)
                acc[i][j] = __builtin_amdgcn_mfma_f32_16x16x32_bf16(af[i], bf[j], acc[i][j], 0, 0, 0);
    }
    const int pbase = pb * 128 + pw2 + (lane & 15);
#pragma unroll
    for (int i = 0; i < 4; ++i) {
        int o = o0 + ow2 + i * 16 + (lane >> 4) * 4;
#pragma unroll
        for (int r = 0; r < 4; ++r) {
            float bias = qbias[o + r];
            ushort* dst = qkv + ((size_t)b * 768 + o + r) * 4096 + pbase;
#pragma unroll
            for (int j = 0; j < 4; ++j)
                dst[j * 16] = f2b(acc[i][j][r] + bias);
        }
    }
}

// ---------------- K4: agent pooling, coalesced, bf16 in ----------------
__global__ __launch_bounds__(256) void k_pool(const ushort* __restrict__ qkv, float* __restrict__ ap) {
    const int bid = blockIdx.x;
    const int b = bid >> 8, c = bid & 255;
    const int t = threadIdx.x;
    const int y = t >> 2, xq = t & 3;
    __shared__ float lp[64][8];
    const ushort* qp = qkv + ((size_t)b * 768 + c) * 4096 + y * 64 + xq * 16;
    short8 a0 = *(const short8*)(qp);
    short8 a1 = *(const short8*)(qp + 8);
    float s0 = 0, s1 = 0;
#pragma unroll
    for (int j = 0; j < 8; ++j) s0 += b2f((ushort)a0[j]);
#pragma unroll
    for (int j = 0; j < 8; ++j) s1 += b2f((ushort)a1[j]);
    lp[y][xq * 2] = s0;
    lp[y][xq * 2 + 1] = s1;
    __syncthreads();
    if (t < 64) {
        int py = t >> 3, px = t & 7;
        float s = 0;
#pragma unroll
        for (int r = 0; r < 8; ++r) s += lp[py * 8 + r][px];
        ap[((size_t)b * 256 + c) * 64 + t] = s * (1.0f / 64.0f);
    }
}

// ---------------- K5: stage-1 attention partials, bf16 in ----------------
__global__ __launch_bounds__(256) void k_att1(const ushort* __restrict__ qkv, const float* __restrict__ ap,
                                              float* __restrict__ attn_g, float* __restrict__ s_g) {
    const int bid0 = blockIdx.x;
    const int bid = (bid0 & 7) * 64 + (bid0 >> 3);
    const int seg = bid & 7, h = (bid >> 3) & 7, b = bid >> 6;
    const int t = threadIdx.x;
    __shared__ float a_s[64][36];
    __shared__ ushort EL[256][68];
    __shared__ ushort vL[256][40];
#pragma unroll
    for (int i = 0; i < 8; ++i) {
        int idx = i * 256 + t;
        int n = idx & 63, d = idx >> 6;
        a_s[n][d] = ap[((size_t)b * 256 + h * 32 + d) * 64 + n] * SCALE;
    }
    const ushort* kb = qkv + ((size_t)b * 768 + 256 + h * 32) * 4096;
    const ushort* vb = qkv + ((size_t)b * 768 + 512 + h * 32) * 4096;
    const int n_own = t >> 2;
    const int dl = t & 3;
    float accr[8] = {0, 0, 0, 0, 0, 0, 0, 0};
    float s_acc = 0.f;
    __syncthreads();
    for (int chunk = 0; chunk < 2; ++chunk) {
        int pix = (seg * 2 + chunk) * 256 + t;
        float kr[32];
#pragma unroll
        for (int d = 0; d < 32; ++d) kr[d] = b2f(kb[(size_t)d * 4096 + pix]);
#pragma unroll
        for (int i = 0; i < 4; ++i) {
            uint4 pk;
            pk.x = (uint32_t)vb[(size_t)(8 * i + 0) * 4096 + pix] |
                   ((uint32_t)vb[(size_t)(8 * i + 1) * 4096 + pix] << 16);
            pk.y = (uint32_t)vb[(size_t)(8 * i + 2) * 4096 + pix] |
                   ((uint32_t)vb[(size_t)(8 * i + 3) * 4096 + pix] << 16);
            pk.z = (uint32_t)vb[(size_t)(8 * i + 4) * 4096 + pix] |
                   ((uint32_t)vb[(size_t)(8 * i + 5) * 4096 + pix] << 16);
            pk.w = (uint32_t)vb[(size_t)(8 * i + 6) * 4096 + pix] |
                   ((uint32_t)vb[(size_t)(8 * i + 7) * 4096 + pix] << 16);
            *(uint4*)&vL[t][i * 8] = pk;
        }
#pragma unroll 1
        for (int np = 0; np < 32; ++np) {
            float l0 = 0, l1 = 0;
#pragma unroll
            for (int dq = 0; dq < 8; ++dq) {
                f32x4 a0 = *(const f32x4*)&a_s[2 * np][dq * 4];
                f32x4 a1 = *(const f32x4*)&a_s[2 * np + 1][dq * 4];
                l0 += a0.x * kr[dq * 4] + a0.y * kr[dq * 4 + 1] + a0.z * kr[dq * 4 + 2] + a0.w * kr[dq * 4 + 3];
                l1 += a1.x * kr[dq * 4] + a1.y * kr[dq * 4 + 1] + a1.z * kr[dq * 4 + 2] + a1.w * kr[dq * 4 + 3];
            }
            uint32_t e2 = (uint32_t)f2b(__expf(l0)) | ((uint32_t)f2b(__expf(l1)) << 16);
            *(uint32_t*)&EL[t][2 * np] = e2;
        }
        __syncthreads();
#pragma unroll 1
        for (int tt = 0; tt < 256; ++tt) {
            float e = b2f(EL[tt][n_own]);
            if (dl == 0) s_acc += e;
            ushort4 va = *(const ushort4*)&vL[tt][dl * 8];
            ushort4 vbx = *(const ushort4*)&vL[tt][dl * 8 + 4];
            accr[0] += e * b2f(va.x);
            accr[1] += e * b2f(va.y);
            accr[2] += e * b2f(va.z);
            accr[3] += e * b2f(va.w);
            accr[4] += e * b2f(vbx.x);
            accr[5] += e * b2f(vbx.y);
            accr[6] += e * b2f(vbx.z);
            accr[7] += e * b2f(vbx.w);
        }
        __syncthreads();
    }
#pragma unroll
    for (int i = 0; i < 8; ++i)
        atomicAdd(&attn_g[(((size_t)b * 8 + h) * 64 + n_own) * 32 + dl * 8 + i], accr[i]);
    if (dl == 0) atomicAdd(&s_g[((size_t)b * 8 + h) * 64 + n_own], s_acc);
}

// ---------------- K6: stage-2 attention + fused depthwise PE, bf16 in/out ----------------
__global__ __launch_bounds__(256) void k_att2(const ushort* __restrict__ qkv, const float* __restrict__ ap,
                                              const float* __restrict__ attn_g, const float* __restrict__ s_g,
                                              const float* __restrict__ pe_w, const float* __restrict__ pe_s,
                                              const float* __restrict__ pe_b, ushort* __restrict__ outp) {
    const int bid0 = blockIdx.x;
    const int bid = (bid0 & 7) * 128 + (bid0 >> 3);
    const int ch = bid & 15, h = (bid >> 4) & 7, b = bid >> 7;
    const int t = threadIdx.x;
    __shared__ float a2[64][36];
    __shared__ float at2[64][36];
    __shared__ float sInv[64];
    __shared__ ushort vsh[32][392];  // 6 rows x 64 of v for 32 channels (row pad for 16B align)
    __shared__ float wsh[32][9];
    __shared__ float psh[32], pbsh[32];
#pragma unroll
    for (int i = 0; i < 8; ++i) {
        int idx = i * 256 + t;
        int n = idx & 63, d = idx >> 6;
        a2[n][d] = ap[((size_t)b * 256 + h * 32 + d) * 64 + n] * SCALE;
    }
    if (t < 64) sInv[t] = 1.0f / s_g[((size_t)b * 8 + h) * 64 + t];
    if (t < 32) {
        int c = h * 32 + t;
#pragma unroll
        for (int p = 0; p < 9; ++p) wsh[t][p] = pe_w[c * 9 + p];
        psh[t] = pe_s[c];
        pbsh[t] = pe_b[c];
    }
    // stage v halo tile: rows ch*4-1 .. ch*4+4 for 32 channels
    {
        int d = t >> 3, j = t & 7;
        const ushort* vsrc = qkv + ((size_t)b * 768 + 512 + h * 32 + d) * 4096 + (ch * 4 - 1) * 64;
        uint4 zz;
        zz.x = zz.y = zz.z = zz.w = 0u;
#pragma unroll
        for (int m = 0; m < 6; ++m) {
            int e0 = (m * 8 + j) * 8;
            bool oob = (ch == 0 && e0 < 64) || (ch == 15 && e0 >= 320);
            uint4 val = oob ? zz : *(const uint4*)(vsrc + e0);
            *(uint4*)&vsh[d][e0] = val;
        }
    }
    __syncthreads();
#pragma unroll
    for (int i = 0; i < 8; ++i) {
        int idx = i * 256 + t;
        int n = idx >> 5, d = idx & 31;
        at2[n][d] = attn_g[(((size_t)b * 8 + h) * 64 + n) * 32 + d] * sInv[n];
    }
    __syncthreads();
    const ushort* qb = qkv + ((size_t)b * 768 + h * 32) * 4096;
    int pix = ch * 256 + t;
    float qr[32];
#pragma unroll
    for (int d = 0; d < 32; ++d) qr[d] = b2f(qb[(size_t)d * 4096 + pix]);
    float oacc[32] = {};
    float s = 0.f;
#pragma unroll 1
    for (int n = 0; n < 64; ++n) {
        float l = 0;
#pragma unroll
        for (int dq = 0; dq < 8; ++dq) {
            f32x4 av = *(const f32x4*)&a2[n][dq * 4];
            l += av.x * qr[dq * 4] + av.y * qr[dq * 4 + 1] + av.z * qr[dq * 4 + 2] + av.w * qr[dq * 4 + 3];
        }
        float e = __expf(l);
        s += e;
#pragma unroll
        for (int dq = 0; dq < 8; ++dq) {
            f32x4 tv = *(const f32x4*)&at2[n][dq * 4];
            oacc[dq * 4] += e * tv.x;
            oacc[dq * 4 + 1] += e * tv.y;
            oacc[dq * 4 + 2] += e * tv.z;
            oacc[dq * 4 + 3] += e * tv.w;
        }
    }
    float si = 1.0f / s;
    const int rr = t >> 6, x = t & 63;
#pragma unroll
    for (int d = 0; d < 32; ++d) {
        float pe = 0;
#pragma unroll
        for (int ky = 0; ky < 3; ++ky) {
            int base = (rr + ky) * 64 + x;
            float mid = b2f(vsh[d][base]);
            float lft = (x > 0) ? b2f(vsh[d][base - 1]) : 0.f;
            float rgt = (x < 63) ? b2f(vsh[d][base + 1]) : 0.f;
            pe += wsh[d][ky * 3] * lft + wsh[d][ky * 3 + 1] * mid + wsh[d][ky * 3 + 2] * rgt;
        }
        outp[((size_t)b * 256 + h * 32 + d) * 4096 + pix] = f2b(oacc[d] * si + psh[d] * pe + pbsh[d]);
    }
}

// ---------------- K8: 1x1 projection as bf16 MFMA GEMM (hi/lo weights), bf16 in ----------------
__global__ __launch_bounds__(256) void k_proj(const ushort* __restrict__ outp, const ushort* __restrict__ Wh,
                                              const ushort* __restrict__ Wl, const float* __restrict__ pbias,
                                              float* __restrict__ out) {
    __shared__ ushort Ah[128][40];
    __shared__ ushort Alo[128][40];
    __shared__ ushort Xl[32][132];
    const int t = threadIdx.x;
    const int bid0 = blockIdx.x;
    const int bid = (bid0 & 7) * 64 + (bid0 >> 3);  // one batch per XCD
    const int b = bid >> 6;
    const int ob = (bid >> 5) & 1;
    const int pb = bid & 31;
    const int o0 = ob << 7;
    const int p0 = pb << 7;
    const int lane = t & 63;
    const int w = t >> 6;
    const int rw = t >> 2, q4 = t & 3;
    const int cl = t >> 3, pg = t & 7;
    const int ow2 = (w >> 1) << 6;
    const int pw2 = (w & 1) << 6;
    const int fr = lane & 15;
    const int fs = (lane >> 4) << 3;

    f32x4 acc[4][4] = {};
    uint4 rah0, rah1, ral0, ral1, rx0, rx1;
    auto loadk = [&](int kc) {
        const size_t awoff = (size_t)(o0 + rw) * 256 + kc * 32 + q4 * 8;
        rah0 = *(const uint4*)(Wh + awoff);
        rah1 = *(const uint4*)(Wh + awoff + (size_t)64 * 256);
        ral0 = *(const uint4*)(Wl + awoff);
        ral1 = *(const uint4*)(Wl + awoff + (size_t)64 * 256);
        const ushort* xsrc = outp + ((size_t)b * 256 + kc * 32 + cl) * 4096 + p0 + pg * 16;
        rx0 = *(const uint4*)xsrc;
        rx1 = *(const uint4*)(xsrc + 8);
    };
    loadk(0);
    for (int kc = 0; kc < 8; ++kc) {
        if (kc) __syncthreads();
        *(uint4*)&Ah[rw][q4 * 8] = rah0;
        *(uint4*)&Ah[rw + 64][q4 * 8] = rah1;
        *(uint4*)&Alo[rw][q4 * 8] = ral0;
        *(uint4*)&Alo[rw + 64][q4 * 8] = ral1;
        *(uint4*)&Xl[cl][pg * 16] = rx0;
        *(uint4*)&Xl[cl][pg * 16 + 8] = rx1;
        __syncthreads();
        if (kc < 7) loadk(kc + 1);
        short8 ah[4], al[4], bf[4];
#pragma unroll
        for (int i = 0; i < 4; ++i) {
            ah[i] = *(const short8*)&Ah[ow2 + i * 16 + fr][fs];
            al[i] = *(const short8*)&Alo[ow2 + i * 16 + fr][fs];
        }
#pragma unroll
        for (int j = 0; j < 4; ++j) {
            int pl = pw2 + j * 16 + fr;
#pragma unroll
            for (int kk = 0; kk < 8; ++kk) bf[j][kk] = (short)Xl[fs + kk][pl];
        }
#pragma unroll
        for (int i = 0; i < 4; ++i)
#pragma unroll
            for (int j = 0; j < 4; ++j) {
                acc[i][j] = __builtin_amdgcn_mfma_f32_16x16x32_bf16(ah[i], bf[j], acc[i][j], 0, 0, 0);
                acc[i][j] = __builtin_amdgcn_mfma_f32_16x16x32_bf16(al[i], bf[j], acc[i][j], 0, 0, 0);
            }
    }
    const int pbase = p0 + pw2 + (lane & 15);
#pragma unroll
    for (int i = 0; i < 4; ++i) {
        int o = o0 + ow2 + i * 16 + (lane >> 4) * 4;
#pragma unroll
        for (int r = 0; r < 4; ++r) {
            float bias = pbias[o + r];
            float* dst = out + ((size_t)b * 256 + o + r) * 4096 + pbase;
#pragma unroll
            for (int j = 0; j < 4; ++j)
                dst[j * 16] = acc[i][j][r] + bias;
        }
    }
}

extern "C" void kernel_launch(void* const* d_in, const int* in_sizes, int n_in,
                              void* d_out, int out_size, void* d_ws, size_t ws_size,
                              hipStream_t stream) {
    const float* x = (const float*)d_in[0];
    const float* qkv_w = (const float*)d_in[1];
    const float* qkv_s = (const float*)d_in[2];
    const float* qkv_b = (const float*)d_in[3];
    const float* pe_w = (const float*)d_in[4];
    const float* pe_s = (const float*)d_in[5];
    const float* pe_b = (const float*)d_in[6];
    const float* proj_w = (const float*)d_in[7];
    const float* proj_s = (const float*)d_in[8];
    const float* proj_b = (const float*)d_in[9];
    float* out = (float*)d_out;

    char* ws = (char*)d_ws;
    ushort* xp = (ushort*)(ws);                 // 17,842,176 B : padded NHWC bf16 input
    ushort* Wa = (ushort*)(ws + 17842176);      //  3,538,944 B : folded qkv weights bf16
    ushort* qkvb = (ushort*)(ws + 21381120);    // 50,331,648 B : qkv activations bf16
    float* apool = (float*)(ws + 71712768);     //    524,288 B : agent tokens f32
    float* attn_g = (float*)(ws + 72237056);    //    524,288 B : stage-1 partial numerators
    float* s_g = (float*)(ws + 72761344);       //     16,384 B : stage-1 partial denominators
    ushort* outpb = (ushort*)(ws + 72777728);   // 16,777,216 B : pre-projection output bf16
    ushort* Wh = (ushort*)(ws + 89554944);      //    131,072 B
    ushort* Wl = (ushort*)(ws + 89686016);      //    131,072 B

    hipMemsetAsync(xp, 0, 17842176, stream);
    hipMemsetAsync(attn_g, 0, 524288 + 16384, stream);
    k_pad<<<512, 256, 0, stream>>>(x, xp);
    k_foldw<<<768, 256, 0, stream>>>(qkv_w, qkv_s, Wa);
    k_foldp<<<256, 256, 0, stream>>>(proj_w, proj_s, Wh, Wl);
    k_conv<<<1536, 256, 0, stream>>>(xp, Wa, qkv_b, qkvb);
    k_pool<<<2048, 256, 0, stream>>>(qkvb, apool);
    k_att1<<<512, 256, 0, stream>>>(qkvb, apool, attn_g, s_g);
    k_att2<<<1024, 256, 0, stream>>>(qkvb, apool, attn_g, s_g, pe_w, pe_s, pe_b, outpb);
    k_proj<<<512, 256, 0, stream>>>(outpb, Wh, Wl, proj_b, out);
}